// Round 2
// baseline (3431.907 us; speedup 1.0000x reference)
//
#include <hip/hip_runtime.h>

#define B_ 64
#define T_ 2048
#define F_ 8
#define H_ 128
#define G_ 512   // 4*H

typedef _Float16 v2h __attribute__((ext_vector_type(2)));

// pack two fp32 into one dword of two f16 (RTN via cast)
__device__ __forceinline__ unsigned pk2h(float lo, float hi) {
    v2h p;
    p[0] = (_Float16)lo;
    p[1] = (_Float16)hi;
    return __builtin_bit_cast(unsigned, p);
}

#if __has_builtin(__builtin_amdgcn_fdot2)
__device__ __forceinline__ float fdot2a(unsigned a, unsigned b, float c) {
    return __builtin_amdgcn_fdot2(__builtin_bit_cast(v2h, a),
                                  __builtin_bit_cast(v2h, b), c, false);
}
#else
__device__ __forceinline__ float fdot2a(unsigned a, unsigned b, float c) {
    v2h av = __builtin_bit_cast(v2h, a);
    v2h bv = __builtin_bit_cast(v2h, b);
    c += (float)av[0] * (float)bv[0];
    c += (float)av[1] * (float)bv[1];
    return c;
}
#endif

__device__ __forceinline__ float sigm(float x) {
    return 1.0f / (1.0f + __expf(-x));
}
__device__ __forceinline__ float tanh_f(float x) {
    // tanh(x) = 1 - 2/(e^{2x}+1); overflow-safe
    float e = __expf(2.0f * x);
    return 1.0f - 2.0f / (e + 1.0f);
}

__global__ __launch_bounds__(512, 2)
void lstm2_fused_kernel(const float* __restrict__ x,
                        const float* __restrict__ wih0,
                        const float* __restrict__ whh0,
                        const float* __restrict__ bih0,
                        const float* __restrict__ bhh0,
                        const float* __restrict__ wih1,
                        const float* __restrict__ whh1,
                        const float* __restrict__ bih1,
                        const float* __restrict__ bhh1,
                        const float* __restrict__ wlin,
                        const float* __restrict__ blin,
                        float* __restrict__ out)
{
    __shared__ __align__(16) unsigned x_lds[T_ * F_ / 2];  // f16-pair packed x: 32 KB
    __shared__ __align__(16) unsigned h0_p[H_ / 2];        // h0 as packed f16 pairs
    __shared__ __align__(16) unsigned h1_p[H_ / 2];        // h1 as packed f16 pairs
    __shared__ __align__(16) float gates[G_];              // activated gate values
    __shared__ __align__(16) unsigned wlin_p[G_];          // w_lin packed f16 pairs
    __shared__ float blin_f[F_];

    const int tid = threadIdx.x;   // 0..511 == gate row for both layers
    const int b = blockIdx.x;      // batch element

    // ---- stage x[b] (fp32) into LDS as packed f16 pairs ----
    const float4* xp = (const float4*)(x + (size_t)b * T_ * F_);
    #pragma unroll
    for (int i = 0; i < 8; ++i) {
        int idx = tid + i * 512;          // float4 index, 4096 total
        float4 v = xp[idx];
        x_lds[idx * 2 + 0] = pk2h(v.x, v.y);
        x_lds[idx * 2 + 1] = pk2h(v.z, v.w);
    }

    // ---- per-thread weight rows -> VGPRs (packed f16 pairs) ----
    unsigned rwih0[4];
    {
        const float4* p = (const float4*)(wih0 + (size_t)tid * F_);
        float4 v0 = p[0], v1 = p[1];
        rwih0[0] = pk2h(v0.x, v0.y); rwih0[1] = pk2h(v0.z, v0.w);
        rwih0[2] = pk2h(v1.x, v1.y); rwih0[3] = pk2h(v1.z, v1.w);
    }
    unsigned rwhh0[64], rwih1[64], rwhh1[64];
    {
        const float4* p = (const float4*)(whh0 + (size_t)tid * H_);
        #pragma unroll
        for (int i = 0; i < 32; ++i) {
            float4 v = p[i];
            rwhh0[i * 2 + 0] = pk2h(v.x, v.y);
            rwhh0[i * 2 + 1] = pk2h(v.z, v.w);
        }
    }
    {
        const float4* p = (const float4*)(wih1 + (size_t)tid * H_);
        #pragma unroll
        for (int i = 0; i < 32; ++i) {
            float4 v = p[i];
            rwih1[i * 2 + 0] = pk2h(v.x, v.y);
            rwih1[i * 2 + 1] = pk2h(v.z, v.w);
        }
    }
    {
        const float4* p = (const float4*)(whh1 + (size_t)tid * H_);
        #pragma unroll
        for (int i = 0; i < 32; ++i) {
            float4 v = p[i];
            rwhh1[i * 2 + 0] = pk2h(v.x, v.y);
            rwhh1[i * 2 + 1] = pk2h(v.z, v.w);
        }
    }
    const float bias0 = bih0[tid] + bhh0[tid];
    const float bias1 = bih1[tid] + bhh1[tid];

    // w_lin: [8][128] fp32 -> 512 packed pairs; pair p = f*64 + k covers h = 2k,2k+1
    {
        const float2* p = (const float2*)wlin;
        float2 v = p[tid];
        wlin_p[tid] = pk2h(v.x, v.y);
    }
    if (tid < F_) blin_f[tid] = blin[tid];
    if (tid < H_ / 2) { h0_p[tid] = 0u; h1_p[tid] = 0u; }
    __syncthreads();

    const bool is_g_gate = ((tid >> 7) == 2);   // rows 256..383 are the 'g' (tanh) gate
    float c0 = 0.0f, c1 = 0.0f;                 // cell state, owned by tid < 128

    for (int t = 0; t < T_; ++t) {
        // ---------- layer 0: gate pre-activation ----------
        float acc0 = bias0, acc1 = 0.0f;
        {
            uint4 xv = *(const uint4*)&x_lds[t * 4];
            acc0 = fdot2a(rwih0[0], xv.x, acc0);
            acc1 = fdot2a(rwih0[1], xv.y, acc1);
            acc0 = fdot2a(rwih0[2], xv.z, acc0);
            acc1 = fdot2a(rwih0[3], xv.w, acc1);
        }
        #pragma unroll
        for (int k = 0; k < 16; ++k) {
            uint4 hv = *(const uint4*)&h0_p[k * 4];
            acc0 = fdot2a(rwhh0[k * 4 + 0], hv.x, acc0);
            acc1 = fdot2a(rwhh0[k * 4 + 1], hv.y, acc1);
            acc0 = fdot2a(rwhh0[k * 4 + 2], hv.z, acc0);
            acc1 = fdot2a(rwhh0[k * 4 + 3], hv.w, acc1);
        }
        {
            float pre = acc0 + acc1;
            gates[tid] = is_g_gate ? tanh_f(pre) : sigm(pre);
        }
        __syncthreads();

        // ---------- layer 0: cell/hidden update ----------
        if (tid < H_) {
            float gi = gates[tid];
            float gf = gates[tid + 128];
            float gg = gates[tid + 256];
            float go = gates[tid + 384];
            c0 = gf * c0 + gi * gg;
            float hh = go * tanh_f(c0);
            ((_Float16*)h0_p)[tid] = (_Float16)hh;
        }
        __syncthreads();

        // ---------- layer 1: gate pre-activation (fused input + recurrent) ----------
        acc0 = bias1; acc1 = 0.0f;
        #pragma unroll
        for (int k = 0; k < 16; ++k) {
            uint4 hv = *(const uint4*)&h0_p[k * 4];
            acc0 = fdot2a(rwih1[k * 4 + 0], hv.x, acc0);
            acc1 = fdot2a(rwih1[k * 4 + 1], hv.y, acc1);
            acc0 = fdot2a(rwih1[k * 4 + 2], hv.z, acc0);
            acc1 = fdot2a(rwih1[k * 4 + 3], hv.w, acc1);
        }
        #pragma unroll
        for (int k = 0; k < 16; ++k) {
            uint4 hv = *(const uint4*)&h1_p[k * 4];
            acc0 = fdot2a(rwhh1[k * 4 + 0], hv.x, acc0);
            acc1 = fdot2a(rwhh1[k * 4 + 1], hv.y, acc1);
            acc0 = fdot2a(rwhh1[k * 4 + 2], hv.z, acc0);
            acc1 = fdot2a(rwhh1[k * 4 + 3], hv.w, acc1);
        }
        {
            float pre = acc0 + acc1;
            gates[tid] = is_g_gate ? tanh_f(pre) : sigm(pre);
        }
        __syncthreads();

        // ---------- layer 1: cell/hidden update ----------
        if (tid < H_) {
            float gi = gates[tid];
            float gf = gates[tid + 128];
            float gg = gates[tid + 256];
            float go = gates[tid + 384];
            c1 = gf * c1 + gi * gg;
            float hh = go * tanh_f(c1);
            ((_Float16*)h1_p)[tid] = (_Float16)hh;
        }
        __syncthreads();

        // ---------- output linear: wave 0 only ----------
        if (tid < 64) {
            int fo = tid >> 3;      // output feature 0..7
            int l  = tid & 7;       // 8 lanes per feature, 16 h-elems each
            float a = 0.0f;
            #pragma unroll
            for (int jj = 0; jj < 8; ++jj) {
                a = fdot2a(wlin_p[fo * 64 + l * 8 + jj], h1_p[l * 8 + jj], a);
            }
            a += __shfl_down(a, 4, 8);
            a += __shfl_down(a, 2, 8);
            a += __shfl_down(a, 1, 8);
            if (l == 0) {
                out[((size_t)b * T_ + t) * F_ + fo] = a + blin_f[fo];
            }
        }
    }
}

extern "C" void kernel_launch(void* const* d_in, const int* in_sizes, int n_in,
                              void* d_out, int out_size, void* d_ws, size_t ws_size,
                              hipStream_t stream) {
    const float* x    = (const float*)d_in[0];
    const float* wih0 = (const float*)d_in[1];
    const float* whh0 = (const float*)d_in[2];
    const float* bih0 = (const float*)d_in[3];
    const float* bhh0 = (const float*)d_in[4];
    const float* wih1 = (const float*)d_in[5];
    const float* whh1 = (const float*)d_in[6];
    const float* bih1 = (const float*)d_in[7];
    const float* bhh1 = (const float*)d_in[8];
    const float* wlin = (const float*)d_in[9];
    const float* blin = (const float*)d_in[10];
    float* out = (float*)d_out;

    lstm2_fused_kernel<<<dim3(B_), dim3(512), 0, stream>>>(
        x, wih0, whh0, bih0, bhh0, wih1, whh1, bih1, bhh1, wlin, blin, out);
}